// Round 13
// baseline (42.762 us; speedup 1.0000x reference)
//
#include <hip/hip_runtime.h>

#define LAMB_COORD 5.0f
#define LAMB_NOOBJ 0.5f
#define GEPS 1e-7f

// gt/pred: (B=16384, C=30, H=7, W=7) fp32. Record = 1470 floats = 30ch x 49 cells.
// 512 blocks x 512 threads, RPB=32 records/block (R12 geometry).
// Phase A (NEW): double-buffered LDS staging in 4 chunk-trips of 8 records:
//   per trip: {barrier; stage(next chunk): contiguous float2 front stream ->
//   LDS; compute(cur chunk): per-cell GIoU/argmax/front loss from LDS}.
//   Stage loads are issued before compute -> HBM latency hides under compute
//   and under the other resident block (2 blocks/CU).
// Phase B: byte-identical to R12's 32-trip class stream (global float2 +
//   LDS app mask).
// LDS: 2*1960*8 (g) + 2*1960*8 (p) + 6272 (app) + 32 = 69 KB -> 2 blocks/CU.

#define RPB        32
#define CHUNK_REC  8
#define NCHUNK     (RPB / CHUNK_REC)     // 4
#define FR2        245                   // float2 per record front (490 floats)
#define CH2        (CHUNK_REC * FR2)     // 1960 float2 per chunk per array
#define CCELLS     (CHUNK_REC * 49)      // 392 cells per chunk
#define CELLS      (RPB * 49)            // 1568
#define CLS2R      490                   // float2 per record class region

__global__ __launch_bounds__(512, 4) void yolo_loss_kernel(
        const float* __restrict__ gt, const float* __restrict__ pred,
        float* __restrict__ out) {
    __shared__ float2 lg2[2 * CH2];      // 31360 B
    __shared__ float2 lp2[2 * CH2];      // 31360 B
    __shared__ float  app[CELLS];        // 6272 B
    __shared__ float  wsum[8];

    const int tid = threadIdx.x;
    const size_t rec0 = (size_t)blockIdx.x * RPB;
    // float2 base of record r: (rec0 + r) * 735
    const float2* __restrict__ gbase = (const float2*)gt;
    const float2* __restrict__ pbase = (const float2*)pred;

    float s = 0.0f;

    // ---- stage chunk 0 into buffer 0 ----
    {
        const size_t cr0 = rec0;  // chunk 0
        #pragma unroll
        for (int k = 0; k < 4; ++k) {
            int idx = tid + k * 512;
            if (idx < CH2) {
                int r = idx / FR2;
                int q = idx - r * FR2;
                size_t go = (cr0 + r) * 735 + q;
                lg2[idx] = gbase[go];
                lp2[idx] = pbase[go];
            }
        }
    }

    // ---- Phase A: 4 chunk-trips, double-buffered ----
    #pragma unroll
    for (int c = 0; c < NCHUNK; ++c) {
        const int cur = c & 1;
        __syncthreads();   // staged chunk c visible; previous compute done

        // stage chunk c+1 into the other buffer (loads issued before compute)
        if (c + 1 < NCHUNK) {
            const int nxt = (c + 1) & 1;
            const size_t crn = rec0 + (size_t)(c + 1) * CHUNK_REC;
            #pragma unroll
            for (int k = 0; k < 4; ++k) {
                int idx = tid + k * 512;
                if (idx < CH2) {
                    int r = idx / FR2;
                    int q = idx - r * FR2;
                    size_t go = (crn + r) * 735 + q;
                    lg2[nxt * CH2 + idx] = gbase[go];
                    lp2[nxt * CH2 + idx] = pbase[go];
                }
            }
        }

        // compute chunk c from LDS
        if (tid < CCELLS) {
            const int rloc = tid / 49;
            const int hw   = tid - rloc * 49;
            const float* __restrict__ g = (const float*)(lg2 + cur * CH2) + rloc * 490 + hw;
            const float* __restrict__ p = (const float*)(lp2 + cur * CH2) + rloc * 490 + hw;

            float gv[10], pv[10];
            #pragma unroll
            for (int cc = 0; cc < 10; ++cc) { gv[cc] = g[cc * 49]; pv[cc] = p[cc * 49]; }

            const float gx1 = gv[0], gy1 = gv[1];
            const float gx2 = gv[0] + gv[2], gy2 = gv[1] + gv[3];
            const float ga  = (gx2 - gx1) * (gy2 - gy1);

            float l[2];
            #pragma unroll
            for (int k = 0; k < 2; ++k) {
                const int o = k * 5;
                float px1 = pv[o + 0], py1 = pv[o + 1];
                float px2 = px1 + pv[o + 2], py2 = py1 + pv[o + 3];
                float ix1 = fmaxf(gx1, px1), iy1 = fmaxf(gy1, py1);
                float ix2 = fminf(gx2, px2), iy2 = fminf(gy2, py2);
                float inter = fmaxf(ix2 - ix1, 0.0f) * fmaxf(iy2 - iy1, 0.0f);
                float pa  = (px2 - px1) * (py2 - py1);
                float uni = ga + pa - inter;
                float iou = inter / (uni + GEPS);
                float cx1 = fminf(gx1, px1), cy1 = fminf(gy1, py1);
                float cx2 = fmaxf(gx2, px2), cy2 = fmaxf(gy2, py2);
                float enc = (cx2 - cx1) * (cy2 - cy1);
                l[k] = 1.0f - (iou - (enc - uni) / (enc + GEPS));
            }

            // jnp.argmax first-max tie-break: arg = 1 iff l2 > l1
            float r0, r1;
            if (l[1] > l[0]) { r0 = 0.0f;   r1 = gv[9]; }
            else             { r0 = gv[4];  r1 = 0.0f;  }
            app[c * CCELLS + tid] = fmaxf(r0, r1);

            float d;
            d = gv[0] - pv[0]; s += d * d * r0 * LAMB_COORD;
            d = gv[1] - pv[1]; s += d * d * r0 * LAMB_COORD;
            d = gv[5] - pv[5]; s += d * d * r1 * LAMB_COORD;
            d = gv[6] - pv[6]; s += d * d * r1 * LAMB_COORD;
            d = sqrtf(gv[2]) - sqrtf(pv[2]); s += d * d * r0 * LAMB_COORD;
            d = sqrtf(gv[3]) - sqrtf(pv[3]); s += d * d * r0 * LAMB_COORD;
            d = sqrtf(gv[7]) - sqrtf(pv[7]); s += d * d * r1 * LAMB_COORD;
            d = sqrtf(gv[8]) - sqrtf(pv[8]); s += d * d * r1 * LAMB_COORD;
            d = gv[4] - pv[4]; { float d2 = d * d; s += d2 * r0 + d2 * (1.0f - r0) * LAMB_NOOBJ; }
            d = gv[9] - pv[9]; { float d2 = d * d; s += d2 * r1 + d2 * (1.0f - r1) * LAMB_NOOBJ; }
        }
    }
    __syncthreads();   // app complete

    // ---- Phase B: class stream (channels 10..29), 32-trip record loop ----
    if (tid < CLS2R) {
        const int q = tid;
        int h0 = (2 * q) % 49;
        int h0n = (h0 == 48) ? 0 : h0 + 1;

        #pragma unroll 4
        for (int rr = 0; rr < RPB; ++rr) {
            const float2* __restrict__ gc = (const float2*)(gt   + (rec0 + rr) * 1470 + 490);
            const float2* __restrict__ pc = (const float2*)(pred + (rec0 + rr) * 1470 + 490);
            const int ab = rr * 49;

            float2 ga2 = gc[q];
            float2 pa2 = pc[q];
            float a0 = app[ab + h0];
            float a1 = app[ab + h0n];
            float d0 = ga2.x - pa2.x;
            float d1 = ga2.y - pa2.y;
            s += d0 * d0 * a0 + d1 * d1 * a1;
        }
    }

    // ---- Reduce: wave shuffle -> LDS -> one atomic per block ----
    #pragma unroll
    for (int off = 32; off > 0; off >>= 1)
        s += __shfl_down(s, off, 64);

    const int lane = tid & 63;
    const int wid  = tid >> 6;
    if (lane == 0) wsum[wid] = s;
    __syncthreads();
    if (tid == 0) {
        float b = 0.0f;
        #pragma unroll
        for (int w = 0; w < 8; ++w) b += wsum[w];
        atomicAdd(out, b);
    }
}

extern "C" void kernel_launch(void* const* d_in, const int* in_sizes, int n_in,
                              void* d_out, int out_size, void* d_ws, size_t ws_size,
                              hipStream_t stream) {
    const float* gt   = (const float*)d_in[0];
    const float* pred = (const float*)d_in[1];
    float* out = (float*)d_out;

    const int B = in_sizes[0] / 1470;    // 16384
    const int grid = B / RPB;            // 512

    hipMemsetAsync(out, 0, sizeof(float) * out_size, stream);
    yolo_loss_kernel<<<grid, 512, 0, stream>>>(gt, pred, out);
}

// Round 14
// 39.803 us; speedup vs baseline: 1.0744x; 1.0744x over previous
//
#include <hip/hip_runtime.h>

#define LAMB_COORD 5.0f
#define LAMB_NOOBJ 0.5f
#define GEPS 1e-7f

// gt/pred: (B=16384, C=30, H=7, W=7) fp32. Record = 1470 floats = 30ch x 49 cells.
// R12 geometry (512 blocks x 512 threads, RPB=32, exactly 2 blocks/CU), with
// phase A rewritten as an explicit 4-stage register double-buffer pipeline:
//   prologue: issue trip0 -> bufA
//   stage t:  issue trip(t+1) -> other buf; sched_barrier; compute trip t
// The next-trip loads are live across the current compute -> the allocator
// must keep ~20 loads in flight per thread (structural, can't be recycled).
// Phase B: byte-identical to R12's 32-trip class stream.

#define RPB   32
#define CELLS (RPB * 49)          // 1568 = 3*512 + 32
#define CLS2R 490                 // float2 per record class region

__device__ __forceinline__ void issue_front(const float* __restrict__ gt,
                                            const float* __restrict__ pred,
                                            size_t rec0, int cell,
                                            float gv[10], float pv[10]) {
    const int rr = cell / 49;
    const int hw = cell - rr * 49;
    const float* __restrict__ g = gt   + (rec0 + rr) * 1470 + hw;
    const float* __restrict__ p = pred + (rec0 + rr) * 1470 + hw;
    #pragma unroll
    for (int c = 0; c < 10; ++c) { gv[c] = g[c * 49]; pv[c] = p[c * 49]; }
}

__device__ __forceinline__ float cell_front(const float gv[10], const float pv[10],
                                            float& appears) {
    const float gx1 = gv[0], gy1 = gv[1];
    const float gx2 = gv[0] + gv[2], gy2 = gv[1] + gv[3];
    const float ga  = (gx2 - gx1) * (gy2 - gy1);

    float l[2];
    #pragma unroll
    for (int k = 0; k < 2; ++k) {
        const int o = k * 5;
        float px1 = pv[o + 0], py1 = pv[o + 1];
        float px2 = px1 + pv[o + 2], py2 = py1 + pv[o + 3];
        float ix1 = fmaxf(gx1, px1), iy1 = fmaxf(gy1, py1);
        float ix2 = fminf(gx2, px2), iy2 = fminf(gy2, py2);
        float inter = fmaxf(ix2 - ix1, 0.0f) * fmaxf(iy2 - iy1, 0.0f);
        float pa  = (px2 - px1) * (py2 - py1);
        float uni = ga + pa - inter;
        float iou = inter / (uni + GEPS);
        float cx1 = fminf(gx1, px1), cy1 = fminf(gy1, py1);
        float cx2 = fmaxf(gx2, px2), cy2 = fmaxf(gy2, py2);
        float enc = (cx2 - cx1) * (cy2 - cy1);
        l[k] = 1.0f - (iou - (enc - uni) / (enc + GEPS));
    }

    // jnp.argmax first-max tie-break: arg = 1 iff l2 > l1
    float r0, r1;
    if (l[1] > l[0]) { r0 = 0.0f;   r1 = gv[9]; }
    else             { r0 = gv[4];  r1 = 0.0f;  }
    appears = fmaxf(r0, r1);

    float t = 0.0f;
    float d;
    d = gv[0] - pv[0]; t += d * d * r0 * LAMB_COORD;
    d = gv[1] - pv[1]; t += d * d * r0 * LAMB_COORD;
    d = gv[5] - pv[5]; t += d * d * r1 * LAMB_COORD;
    d = gv[6] - pv[6]; t += d * d * r1 * LAMB_COORD;
    d = sqrtf(gv[2]) - sqrtf(pv[2]); t += d * d * r0 * LAMB_COORD;
    d = sqrtf(gv[3]) - sqrtf(pv[3]); t += d * d * r0 * LAMB_COORD;
    d = sqrtf(gv[7]) - sqrtf(pv[7]); t += d * d * r1 * LAMB_COORD;
    d = sqrtf(gv[8]) - sqrtf(pv[8]); t += d * d * r1 * LAMB_COORD;
    d = gv[4] - pv[4]; { float d2 = d * d; t += d2 * r0 + d2 * (1.0f - r0) * LAMB_NOOBJ; }
    d = gv[9] - pv[9]; { float d2 = d * d; t += d2 * r1 + d2 * (1.0f - r1) * LAMB_NOOBJ; }
    return t;
}

__global__ __launch_bounds__(512, 4) void yolo_loss_kernel(
        const float* __restrict__ gt, const float* __restrict__ pred,
        float* __restrict__ out) {
    __shared__ float app[CELLS];  // 6272 B
    __shared__ float wsum[8];

    const int tid = threadIdx.x;
    const size_t rec0 = (size_t)blockIdx.x * RPB;

    float s = 0.0f;

    // ---- Phase A: explicit 4-stage register double-buffer pipeline ----
    const int cell0 = tid;
    const int cell1 = tid + 512;
    const int cell2 = tid + 1024;
    const int cell3 = tid + 1536;                      // valid only for tid < 32
    const int cell3c = (cell3 < CELLS) ? cell3 : (CELLS - 1);

    float gA[10], pA[10], gB[10], pB[10];

    issue_front(gt, pred, rec0, cell0, gA, pA);        // prologue

    issue_front(gt, pred, rec0, cell1, gB, pB);        // stage 0
    __builtin_amdgcn_sched_barrier(0);
    { float ap; float t = cell_front(gA, pA, ap); app[cell0] = ap; s += t; }

    issue_front(gt, pred, rec0, cell2, gA, pA);        // stage 1
    __builtin_amdgcn_sched_barrier(0);
    { float ap; float t = cell_front(gB, pB, ap); app[cell1] = ap; s += t; }

    issue_front(gt, pred, rec0, cell3c, gB, pB);       // stage 2
    __builtin_amdgcn_sched_barrier(0);
    { float ap; float t = cell_front(gA, pA, ap); app[cell2] = ap; s += t; }

    { float ap; float t = cell_front(gB, pB, ap);      // stage 3 (masked tail)
      if (cell3 < CELLS) { app[cell3] = ap; s += t; } }

    __syncthreads();

    // ---- Phase B: class stream (channels 10..29), 32-trip record loop ----
    if (tid < CLS2R) {
        const int q = tid;
        int h0 = (2 * q) % 49;
        int h0n = (h0 == 48) ? 0 : h0 + 1;

        #pragma unroll 4
        for (int rr = 0; rr < RPB; ++rr) {
            const float2* __restrict__ gc = (const float2*)(gt   + (rec0 + rr) * 1470 + 490);
            const float2* __restrict__ pc = (const float2*)(pred + (rec0 + rr) * 1470 + 490);
            const int ab = rr * 49;

            float2 ga2 = gc[q];
            float2 pa2 = pc[q];
            float a0 = app[ab + h0];
            float a1 = app[ab + h0n];
            float d0 = ga2.x - pa2.x;
            float d1 = ga2.y - pa2.y;
            s += d0 * d0 * a0 + d1 * d1 * a1;
        }
    }

    // ---- Reduce: wave shuffle -> LDS -> one atomic per block ----
    #pragma unroll
    for (int off = 32; off > 0; off >>= 1)
        s += __shfl_down(s, off, 64);

    const int lane = tid & 63;
    const int wid  = tid >> 6;
    if (lane == 0) wsum[wid] = s;
    __syncthreads();
    if (tid == 0) {
        float b = 0.0f;
        #pragma unroll
        for (int w = 0; w < 8; ++w) b += wsum[w];
        atomicAdd(out, b);
    }
}

extern "C" void kernel_launch(void* const* d_in, const int* in_sizes, int n_in,
                              void* d_out, int out_size, void* d_ws, size_t ws_size,
                              hipStream_t stream) {
    const float* gt   = (const float*)d_in[0];
    const float* pred = (const float*)d_in[1];
    float* out = (float*)d_out;

    const int B = in_sizes[0] / 1470;    // 16384
    const int grid = B / RPB;            // 512

    hipMemsetAsync(out, 0, sizeof(float) * out_size, stream);
    yolo_loss_kernel<<<grid, 512, 0, stream>>>(gt, pred, out);
}